// Round 7
// baseline (540.224 us; speedup 1.0000x reference)
//
#include <hip/hip_runtime.h>
#include <math.h>

#define TPB 256
#define TPB_P 512
#define TPB_A 512            // k_agg: 64KB acc -> 2 blocks/CU, 16 waves/CU (R4 measured best)
#define LRATE 0.005f

// Final bucketing: 1024 nodes per bucket (round-4 measured optimum)
#define LOG_NPB 10
#define NPB (1 << LOG_NPB)
#define CAP 14336            // mean ~10225 edges/bucket; +40 sigma

// Two-level partition (round-5 lesson: 1-level scatter to many buckets had
// short runs -> 4x write amplification). Level sizes keep every run >= 256B.
#define LOG_SUP 13
#define NS1 64               // level-1 bins: dst>>13, 8192 nodes/super
#define CAP1 90112           // 22*4096; mean 81920, +28 sigma
#define NS2 8                // level-2 bins: 8 buckets per super
#define CHUNK 4096
#define CPT (CHUNK / TPB_P)  // 8

// src-tile sort: tile = src>>13 == rec>>23. k_agg consumes 512-edge chunks
// (~0.8MB hp window) -> all co-resident blocks sweep in phase, L2-resident.
// (Measured twice, r3/r6: >512-edge windows -> FETCH +20-110MB regression.)
#define NTILE 64

// fixed-point accumulator scale (LDS int atomics are native; float LDS
// atomicAdd compiles to a CAS loop -- the round-1 regression)
#define FXS  65536.0f
#define FXSI (1.0f / 65536.0f)
// per-addend bias for packed u64 adds: guarantees positive 32-bit halves so
// low word never carries into high. |a| < 2^19, deg <= ~40 -> sum < 2^26.
#define FXBIAS (1 << 20)

// ---------------------------------------------------------------------------
// fp8 e4m3fn helpers (OCP).
#if __has_builtin(__builtin_amdgcn_cvt_f32_fp8) && __has_builtin(__builtin_amdgcn_cvt_pk_fp8_f32)
__device__ __forceinline__ float fp8_dec(unsigned char v) {
    return __builtin_amdgcn_cvt_f32_fp8((int)v, 0);
}
__device__ __forceinline__ unsigned fp8_pk4(float a, float b, float c, float d) {
    int w = __builtin_amdgcn_cvt_pk_fp8_f32(a, b, 0, false);
    w = __builtin_amdgcn_cvt_pk_fp8_f32(c, d, w, true);
    return (unsigned)w;
}
#else
__device__ __forceinline__ unsigned char fp8_enc1(float f) {
    unsigned u = __float_as_uint(f);
    unsigned s = (u >> 24) & 0x80u;
    u &= 0x7FFFFFFFu;
    if (u >= 0x43E00000u) return (unsigned char)(s | 0x7E);
    if (u < 0x3C800000u) {
        float a = __uint_as_float(u);
        int m = (int)rintf(a * 512.f);
        return (unsigned char)(s | (unsigned)m);
    }
    unsigned mant = u & 0x7FFFFFu;
    unsigned rest = mant & 0xFFFFFu;
    unsigned keep = u >> 20;
    keep += (rest > 0x80000u || (rest == 0x80000u && (keep & 1u))) ? 1u : 0u;
    int eb = (int)(keep >> 3) - 127 + 7;
    return (unsigned char)(s | (unsigned)((eb << 3) | (int)(keep & 7u)));
}
__device__ __forceinline__ float fp8_dec(unsigned char v) {
    unsigned s = ((unsigned)(v & 0x80u)) << 24;
    unsigned e = (v >> 3) & 0xFu;
    unsigned m = v & 7u;
    if (e == 0) {
        float r = (float)m * 0.001953125f;
        return (v & 0x80u) ? -r : r;
    }
    return __uint_as_float(s | ((e + 120u) << 23) | (m << 20));
}
__device__ __forceinline__ unsigned fp8_pk4(float a, float b, float c, float d) {
    return (unsigned)fp8_enc1(a) | ((unsigned)fp8_enc1(b) << 8) |
           ((unsigned)fp8_enc1(c) << 16) | ((unsigned)fp8_enc1(d) << 24);
}
#endif

#if __has_builtin(__builtin_amdgcn_cvt_pk_f32_fp8)
typedef float __attribute__((ext_vector_type(2))) f32x2;
__device__ __forceinline__ void fp8_dec4(unsigned w, float& a, float& b, float& c, float& d) {
    f32x2 lo = __builtin_amdgcn_cvt_pk_f32_fp8((int)w, false);
    f32x2 hi = __builtin_amdgcn_cvt_pk_f32_fp8((int)w, true);
    a = lo[0]; b = lo[1]; c = hi[0]; d = hi[1];
}
#else
__device__ __forceinline__ void fp8_dec4(unsigned w, float& a, float& b, float& c, float& d) {
    a = fp8_dec((unsigned char)(w & 0xFFu));
    b = fp8_dec((unsigned char)((w >> 8) & 0xFFu));
    c = fp8_dec((unsigned char)((w >> 16) & 0xFFu));
    d = fp8_dec((unsigned char)((w >> 24) & 0xFFu));
}
#endif

// pack two biased s16.16 addends into one u64 for ds_add_u64
__device__ __forceinline__ unsigned long long pack2(float f0, float f1) {
    unsigned lo = (unsigned)(FXBIAS + (int)(f0 * FXS));
    unsigned hi = (unsigned)(FXBIAS + (int)(f1 * FXS));
    return (unsigned long long)lo | ((unsigned long long)hi << 32);
}

// ---------------------------------------------------------------------------
// K_PART1: level-1 partition by super-bucket (dst >> 13, 64 bins).
// Record = (src << 13) | (dst & 8191) -- exactly 32 bits for src < 2^19.
__global__ __launch_bounds__(TPB_P) void k_part1(const int* __restrict__ src,
                                                 const int* __restrict__ dst,
                                                 int* __restrict__ bcur1,   // [64*16] zeroed
                                                 int* __restrict__ grec1,   // [NS1*CAP1]
                                                 int E) {
    __shared__ int hist[NS1], lstart[NS1], lcur[NS1], gbase[NS1];
    __shared__ int lbuf[CHUNK];
    __shared__ unsigned char bbuf[CHUNK];
    int t = threadIdx.x;
    int chunkBase = blockIdx.x * CHUNK;
    if (t < NS1) hist[t] = 0;
    __syncthreads();

    int myb[CPT], myrec[CPT];
#pragma unroll
    for (int k = 0; k < CPT; k++) {
        int e = chunkBase + k * TPB_P + t;
        if (e < E) {
            int d = dst[e];
            int s = src[e];
            myb[k] = d >> LOG_SUP;
            myrec[k] = (s << LOG_SUP) | (d & ((1 << LOG_SUP) - 1));
            atomicAdd(&hist[myb[k]], 1);
        } else myb[k] = -1;
    }
    __syncthreads();
    if (t == 0) {
        int run = 0;
        for (int k2 = 0; k2 < NS1; k2++) {
            int c = hist[k2]; lstart[k2] = run; lcur[k2] = run; run += c;
        }
    }
    __syncthreads();
    if (t < NS1 && hist[t] > 0) gbase[t] = atomicAdd(&bcur1[t * 16], hist[t]);
    __syncthreads();
#pragma unroll
    for (int k = 0; k < CPT; k++) {
        if (myb[k] >= 0) {
            int p = atomicAdd(&lcur[myb[k]], 1);
            lbuf[p] = myrec[k];
            bbuf[p] = (unsigned char)myb[k];
        }
    }
    __syncthreads();
    int total = E - chunkBase; if (total > CHUNK) total = CHUNK;
    for (int p = t; p < total; p += TPB_P) {
        int b = (int)bbuf[p];
        int pos = gbase[b] + (p - lstart[b]);
        if (pos < CAP1) grec1[(size_t)b * CAP1 + pos] = lbuf[p];
    }
}

// K_PART2: level-2 partition of each super-bucket into its 8 final buckets.
// Record transform (src<<13)|(dst&8191) -> (src<<10)|(dst&1023).
__global__ __launch_bounds__(TPB_P) void k_part2(const int* __restrict__ bcur1,
                                                 const int* __restrict__ grec1,
                                                 int* __restrict__ bcur,
                                                 int* __restrict__ grec) {
    __shared__ int hist[NS2], lstart[NS2], lcur[NS2], gbase[NS2];
    __shared__ int lbuf[CHUNK];
    __shared__ unsigned char bbuf[CHUNK];
    int t = threadIdx.x;
    int s = blockIdx.x;
    int cnt1 = bcur1[s * 16]; if (cnt1 > CAP1) cnt1 = CAP1;
    int chunkBase = blockIdx.y * CHUNK;
    if (chunkBase >= cnt1) return;             // uniform per block
    int total = cnt1 - chunkBase; if (total > CHUNK) total = CHUNK;
    if (t < NS2) hist[t] = 0;
    __syncthreads();

    int myb[CPT], myrec[CPT];
#pragma unroll
    for (int k = 0; k < CPT; k++) {
        int i = chunkBase + k * TPB_P + t;
        if (i < cnt1) {
            int r = grec1[(size_t)s * CAP1 + i];
            int sub = (r >> LOG_NPB) & (NS2 - 1);
            myb[k] = sub;
            myrec[k] = (int)((((unsigned)r) >> LOG_SUP) << LOG_NPB) | (r & (NPB - 1));
            atomicAdd(&hist[sub], 1);
        } else myb[k] = -1;
    }
    __syncthreads();
    if (t == 0) {
        int run = 0;
        for (int k2 = 0; k2 < NS2; k2++) {
            int c = hist[k2]; lstart[k2] = run; lcur[k2] = run; run += c;
        }
    }
    __syncthreads();
    if (t < NS2 && hist[t] > 0) gbase[t] = atomicAdd(&bcur[(s * NS2 + t) * 16], hist[t]);
    __syncthreads();
#pragma unroll
    for (int k = 0; k < CPT; k++) {
        if (myb[k] >= 0) {
            int p = atomicAdd(&lcur[myb[k]], 1);
            lbuf[p] = myrec[k];
            bbuf[p] = (unsigned char)myb[k];
        }
    }
    __syncthreads();
    for (int p = t; p < total; p += TPB_P) {
        int b = (int)bbuf[p];
        int pos = gbase[b] + (p - lstart[b]);
        if (pos < CAP) grec[(size_t)(s * NS2 + b) * CAP + pos] = lbuf[p];
    }
}

// K_SORT: per-bucket counting sort by src-tile (rec >> 23 == src >> 13).
// Also computes deg/dinv. 512 threads, ~119KB LDS.
__global__ __launch_bounds__(TPB_P) void k_sort(int* __restrict__ bcur,
                                                int* __restrict__ grec,
                                                float* __restrict__ dinv, int N) {
    __shared__ int lbuf[CAP];     // 57344 B
    __shared__ int obuf[CAP];     // 57344 B
    __shared__ int deg[NPB];      // 4096 B
    __shared__ int hist[NTILE];
    __shared__ int curp[NTILE];
    int t = threadIdx.x;
    int b = blockIdx.x;
    int cnt = bcur[b * 16]; if (cnt > CAP) cnt = CAP;
    const size_t base = (size_t)b * CAP;

    for (int i = t; i < NTILE; i += TPB_P) hist[i] = 0;
    for (int i = t; i < NPB; i += TPB_P) deg[i] = 0;
    __syncthreads();
    for (int i = t; i < cnt; i += TPB_P) {
        int r = grec[base + i];
        lbuf[i] = r;
        atomicAdd(&deg[r & (NPB - 1)], 1);
        atomicAdd(&hist[((unsigned)r) >> 23], 1);   // int LDS atomic: native
    }
    __syncthreads();
    if (t == 0) {
        int run = 0;
#pragma unroll
        for (int k = 0; k < NTILE; k++) { int c = hist[k]; curp[k] = run; run += c; }
    }
    __syncthreads();
    for (int i = t; i < cnt; i += TPB_P) {
        int r = lbuf[i];
        int p = atomicAdd(&curp[((unsigned)r) >> 23], 1);
        obuf[p] = r;
    }
    __syncthreads();
    for (int i = t; i < cnt; i += TPB_P) grec[base + i] = obuf[i];
    int nodeBase = b << LOG_NPB;
    for (int i = t; i < NPB; i += TPB_P) {
        int node = nodeBase + i;
        if (node < N) dinv[node] = rsqrtf((float)(deg[i] + 1));
    }
}

// ---------------------------------------------------------------------------
// K3: hp = fp8_e4m3( dinv * (x @ W.T) )
__global__ __launch_bounds__(TPB) void k_h(const float* __restrict__ xc,
                                           const float* __restrict__ W,
                                           const float* __restrict__ dinv,
                                           unsigned* __restrict__ hp, int n) {
    __shared__ float sW[256];
    if (threadIdx.x < 256) sW[threadIdx.x] = W[threadIdx.x];
    __syncthreads();
    int i = blockIdx.x * blockDim.x + threadIdx.x;
    int stride = gridDim.x * blockDim.x;
    for (; i < n; i += stride) {
        float x[16];
        const float4* xr = (const float4*)(xc + (size_t)i * 16);
#pragma unroll
        for (int q = 0; q < 4; q++) {
            float4 v = xr[q];
            x[4*q+0] = v.x; x[4*q+1] = v.y; x[4*q+2] = v.z; x[4*q+3] = v.w;
        }
        float di = dinv[i];
        float hv[16];
#pragma unroll
        for (int j = 0; j < 16; j++) {
            float s = 0.f;
#pragma unroll
            for (int k = 0; k < 16; k++) s = fmaf(x[k], sW[j*16 + k], s);
            hv[j] = di * s;
        }
        uint4 w;
        w.x = fp8_pk4(hv[0],  hv[1],  hv[2],  hv[3]);
        w.y = fp8_pk4(hv[4],  hv[5],  hv[6],  hv[7]);
        w.z = fp8_pk4(hv[8],  hv[9],  hv[10], hv[11]);
        w.w = fp8_pk4(hv[12], hv[13], hv[14], hv[15]);
        ((uint4*)hp)[i] = w;
    }
}

// ---------------------------------------------------------------------------
// K_AGG: edge-parallel aggregation + finalize, ONE block per 1024-node
// bucket (r4 config: 2 blocks/CU, 16 waves/CU, 512-edge chunks, FETCH 61.5MB).
// Phase 1: 4 lanes/edge; each lane decodes 4 fp8 features and issues TWO
// ds_add_u64 (feature pairs, biased positive halves) instead of 4 ds_add_u32
// -- halves LDS-pipe instructions, the largest measured pipe component.
// Accumulator pair p (features 2p,2p+1) at accP[p*NPB + (dl^p)].
// Phase 2: finalize removes bias using in-bucket degree recovered from dinv;
// z = relu(dinv*(acc+self)+b); dW/db reduced via red[512][17] overlay.
__global__ __launch_bounds__(TPB_A, 4) void k_agg(const int* __restrict__ bcur,
                                                  const int* __restrict__ grec,
                                                  const float* __restrict__ dinv,
                                                  const unsigned* __restrict__ hp32,
                                                  const float* __restrict__ b,
                                                  const float* __restrict__ xc,
                                                  float* __restrict__ z,
                                                  float* __restrict__ partial,
                                                  int nb, int N) {
    __shared__ unsigned long long accP[8 * NPB];   // 64 KB; red overlay later
    int t = threadIdx.x;
    int bkt = blockIdx.x;
    int cnt = bcur[bkt * 16]; if (cnt > CAP) cnt = CAP;
    const int nodeBase = bkt << LOG_NPB;
    const size_t recBase = (size_t)bkt * CAP;

    for (int i = t; i < 8 * NPB; i += TPB_A) accP[i] = 0ull;
    __syncthreads();

    // ---- Phase 1: edge-parallel scatter (packed biased u64 atomics) ----
    int q = t & 3;          // hp dword q -> features 4q..4q+3 -> pairs 2q, 2q+1
    int gi = t >> 2;        // edge slot 0..127
    int p0 = q * 2;
    int p1 = q * 2 + 1;
    int base = 0;
    for (; base + 512 <= cnt; base += 512) {
        int rec[4];
#pragma unroll
        for (int u = 0; u < 4; u++) rec[u] = grec[recBase + base + u * 128 + gi];
        unsigned w[4];
#pragma unroll
        for (int u = 0; u < 4; u++)
            w[u] = hp32[(size_t)(((unsigned)rec[u]) >> LOG_NPB) * 4 + q];
#pragma unroll
        for (int u = 0; u < 4; u++) {
            int dl = rec[u] & (NPB - 1);
            float f0, f1, f2, f3;
            fp8_dec4(w[u], f0, f1, f2, f3);
            atomicAdd(&accP[p0 * NPB + (dl ^ p0)], pack2(f0, f1));
            atomicAdd(&accP[p1 * NPB + (dl ^ p1)], pack2(f2, f3));
        }
    }
    for (int e = base + gi; e < cnt; e += 128) {
        int rec = grec[recBase + e];
        unsigned w = hp32[(size_t)(((unsigned)rec) >> LOG_NPB) * 4 + q];
        int dl = rec & (NPB - 1);
        float f0, f1, f2, f3;
        fp8_dec4(w, f0, f1, f2, f3);
        atomicAdd(&accP[p0 * NPB + (dl ^ p0)], pack2(f0, f1));
        atomicAdd(&accP[p1 * NPB + (dl ^ p1)], pack2(f2, f3));
    }
    __syncthreads();

    // ---- Phase 2: finalize rows (16 lanes per row, 32 row-groups) ----
    const unsigned char* hpB = (const unsigned char*)hp32;
    const int* accI32 = (const int*)accP;
    int j = t & 15;
    int g0 = t >> 4;        // 0..31 row groups
    int pj = j >> 1;        // pair plane
    int hj = j & 1;         // half within pair
    float bj = b[j];
    float accW[16];
#pragma unroll
    for (int k = 0; k < 16; k++) accW[k] = 0.f;
    float accB = 0.f;

    for (int i = g0; i < NPB; i += 32) {
        int node = nodeBase + i;
        if (node >= N) break;
        float di = dinv[node];
        // in-bucket degree (atomic-add count) recovered from dinv = rsqrt(deg+1)
        int cdeg = (int)rintf(1.0f / (di * di)) - 1;
        int raw = accI32[(pj * NPB + (i ^ pj)) * 2 + hj];
        int ai = raw - cdeg * FXBIAS;                        // remove per-add bias
        float sv = fp8_dec(hpB[(size_t)node * 16 + j]);      // self-loop
        float aj = fmaf((float)ai, FXSI, sv);
        float zj = fmaxf(fmaf(di, aj, bj), 0.f);
        z[(size_t)node * 16 + j] = zj;
        float wdj = 4.f * zj * zj;
        accB += wdj;
        const float4* xrow = (const float4*)(xc + (size_t)node * 16);
        float4 x0 = xrow[0], x1 = xrow[1], x2 = xrow[2], x3 = xrow[3];
        accW[0]  = fmaf(x0.x, wdj, accW[0]);  accW[1]  = fmaf(x0.y, wdj, accW[1]);
        accW[2]  = fmaf(x0.z, wdj, accW[2]);  accW[3]  = fmaf(x0.w, wdj, accW[3]);
        accW[4]  = fmaf(x1.x, wdj, accW[4]);  accW[5]  = fmaf(x1.y, wdj, accW[5]);
        accW[6]  = fmaf(x1.z, wdj, accW[6]);  accW[7]  = fmaf(x1.w, wdj, accW[7]);
        accW[8]  = fmaf(x2.x, wdj, accW[8]);  accW[9]  = fmaf(x2.y, wdj, accW[9]);
        accW[10] = fmaf(x2.z, wdj, accW[10]); accW[11] = fmaf(x2.w, wdj, accW[11]);
        accW[12] = fmaf(x3.x, wdj, accW[12]); accW[13] = fmaf(x3.y, wdj, accW[13]);
        accW[14] = fmaf(x3.z, wdj, accW[14]); accW[15] = fmaf(x3.w, wdj, accW[15]);
    }
    __syncthreads();   // all accP reads done -> safe to alias red onto accP

    float (*red)[17] = (float (*)[17])accP;   // 512*17*4 = 34816B <= 64KB
#pragma unroll
    for (int k = 0; k < 16; k++) red[t][k] = accW[k];
    red[t][16] = accB;
    __syncthreads();
    if (t < 256) {
        int kk = t >> 4;
        int jj = t & 15;
        float s = 0.f;
#pragma unroll
        for (int g = 0; g < 32; g++) s += red[g * 16 + jj][kk];
        partial[(size_t)(kk * 16 + jj) * nb + bkt] = s;
    }
    if (t < 16) {
        float sb = 0.f;
#pragma unroll
        for (int g = 0; g < 32; g++) sb += red[g * 16 + t][16];
        partial[(size_t)(256 + t) * nb + bkt] = sb;
    }
}

// ---------------------------------------------------------------------------
__device__ __forceinline__ float local_loss_f(float g, int positive) {
    const float t = 0.0f;
    if (positive) {
        if (g > t + 10.f) return 0.f;
        if (g < t - 10.f) return t - g;
        return log1pf(expf(t - g));
    } else {
        if (g > t + 10.f) return t + g;
        if (g < t - 10.f) return 0.f;
        return log1pf(expf(g + t));
    }
}

// K_FIN: merged reduce + finalize (one dispatch). 13 waves: wave-per-element
// coalesced sums over nb partials into LDS, then the k_final logic.
__global__ __launch_bounds__(832) void k_fin(const float* __restrict__ W1,
                                             const float* __restrict__ b1,
                                             const float* __restrict__ partial,
                                             const int* __restrict__ positive,
                                             float* __restrict__ outv, int nb) {
    __shared__ float accL[3 * 272];
    int t = threadIdx.x;
    int wid = t >> 6, lane = t & 63;
    for (int e = wid; e < 3 * 272; e += 13) {
        const float* p = partial + (size_t)e * nb;
        float s = 0.f;
        for (int b = lane; b < nb; b += 64) s += p[b];
#pragma unroll
        for (int off = 32; off > 0; off >>= 1) s += __shfl_down(s, off, 64);
        if (lane == 0) accL[e] = s;
    }
    __syncthreads();
    if (t < 256) {
        int jj = t >> 4, kk = t & 15;   // Wc[jj][kk] -= LR * dW[kk][jj]
        float s = 0.f;
#pragma unroll
        for (int l = 0; l < 3; l++) s += accL[l * 272 + kk * 16 + jj];
        outv[1 + t] = W1[t] - LRATE * s;
    }
    if (t < 16) {
        float s = 0.f;
#pragma unroll
        for (int l = 0; l < 3; l++) s += accL[l * 272 + 256 + t];
        outv[257 + t] = b1[t] - LRATE * s;
    }
    if (t == 0) {
        int pos = positive[0];
        float agg = 0.f;
#pragma unroll
        for (int l = 0; l < 3; l++) {
            float g = 0.f;
#pragma unroll
            for (int jj = 0; jj < 16; jj++) g += accL[l * 272 + 256 + jj];
            g *= (1.0f / 64.0f);
            agg += local_loss_f(g, pos);
        }
        outv[0] = agg;
    }
}

extern "C" void kernel_launch(void* const* d_in, const int* in_sizes, int n_in,
                              void* d_out, int out_size, void* d_ws, size_t ws_size,
                              hipStream_t stream) {
    const float* x  = (const float*)d_in[0];
    const int*   ei = (const int*)d_in[1];
    const float* W1 = (const float*)d_in[2];
    const float* b1 = (const float*)d_in[3];
    const float* W2 = (const float*)d_in[4];
    const float* b2 = (const float*)d_in[5];
    const float* W3 = (const float*)d_in[6];
    const float* b3 = (const float*)d_in[7];
    const int* positive = (const int*)d_in[8];
    float* outv = (float*)d_out;

    const int N = in_sizes[0] / 16;
    const int E = in_sizes[1] / 2;
    const int nbuck = (N + NPB - 1) >> LOG_NPB;         // 489 for N=500k
    const int nsuper = (N + (1 << LOG_SUP) - 1) >> LOG_SUP;   // 62
    const int nbpad = nsuper * NS2;                     // 496 (grec/bcur sizing)

    // Workspace carve-out (256B aligned).
    char* ws = (char*)d_ws;
    size_t off = 0;
    auto carve = [&](size_t bytes) -> void* {
        void* p = ws + off;
        off = (off + bytes + 255) & ~(size_t)255;
        return p;
    };
    int*   bcur   = (int*)  carve((size_t)(nbpad + NS1) * 16 * 4);  // bucket + super cursors
    int*   bcur1  = bcur + (size_t)nbpad * 16;
    int*   grec   = (int*)  carve((size_t)nbpad * CAP * 4);   // 28.4 MB, lives all layers
    float* dinv   = (float*)carve((size_t)N * 4);
    float* part   = (float*)carve((size_t)3 * 272 * nbuck * 4);
    unsigned* hp  = (unsigned*)carve((size_t)N * 16);         // fp8 rows, 8 MB
    float* P1     = (float*)carve((size_t)N * 64);
    // grec1 (22.3 MB, dead after k_part2) aliases P2 (32 MB, first written
    // by k_agg in layer 2 -- strictly after k_part2).
    float* P2     = (float*)carve((size_t)N * 64);
    int*   grec1  = (int*)P2;

    hipMemsetAsync(bcur, 0, (size_t)(nbpad + NS1) * 16 * 4, stream);

    const int* src = ei;
    const int* dst = ei + E;

    // --- Two-level partition + src-tile sort (once, reused 3x) ---
    int p1Blocks = (E + CHUNK - 1) / CHUNK;
    k_part1<<<p1Blocks, TPB_P, 0, stream>>>(src, dst, bcur1, grec1, E);
    dim3 g2(nsuper, CAP1 / CHUNK);     // (62, 22)
    k_part2<<<g2, TPB_P, 0, stream>>>(bcur1, grec1, bcur, grec);
    k_sort<<<nbuck, TPB_P, 0, stream>>>(bcur, grec, dinv, N);

    // --- 3 layers ---
    const float* Ws[3] = {W1, W2, W3};
    const float* bss[3] = {b1, b2, b3};
    float* outs[3] = {P1, P2, P1};   // L1: x->P1; L2: P1->P2; L3: P2->P1

    int nodeBlocks = (N + TPB - 1) / TPB;

    const float* xc = x;
    for (int l = 0; l < 3; l++) {
        k_h<<<nodeBlocks, TPB, 0, stream>>>(xc, Ws[l], dinv, hp, N);
        k_agg<<<nbuck, TPB_A, 0, stream>>>(bcur, grec, dinv, hp, bss[l],
                                           xc, outs[l],
                                           part + (size_t)l * 272 * nbuck, nbuck, N);
        xc = outs[l];
    }
    k_fin<<<1, 832, 0, stream>>>(W1, b1, part, positive, outv, nbuck);
}

// Round 8
// 386.622 us; speedup vs baseline: 1.3973x; 1.3973x over previous
//
#include <hip/hip_runtime.h>
#include <math.h>

#define TPB 256
#define TPB_P 512
#define TPB_A 512            // k_agg: 64KB acc -> 2 blocks/CU, 16 waves/CU (R4 measured best)
#define LRATE 0.005f

// Final bucketing: 1024 nodes per bucket (round-4 measured optimum)
#define LOG_NPB 10
#define NPB (1 << LOG_NPB)
#define CAP 14336            // mean ~10225 edges/bucket; +40 sigma

// Two-level partition (round-5 lesson: 1-level scatter to many buckets had
// short runs -> 4x write amplification). Level sizes keep every run >= 256B.
#define LOG_SUP 13
#define NS1 64               // level-1 bins: dst>>13, 8192 nodes/super
#define CAP1 90112           // 22*4096; mean 81920, +28 sigma
#define NS2 8                // level-2 bins: 8 buckets per super
#define CHUNK 4096
#define CPT (CHUNK / TPB_P)  // 8

// src-tile sort: tile = src>>13 == rec>>23. k_agg consumes 512-edge chunks
// (~0.8MB hp window) -> all co-resident blocks sweep in phase, L2-resident.
// (Measured twice, r3/r6: >512-edge windows -> FETCH +20-110MB regression.)
#define NTILE 64

// fixed-point accumulator scale (LDS int atomics are native; float LDS
// atomicAdd compiles to a CAS loop -- the round-1 regression)
#define FXS  65536.0f
#define FXSI (1.0f / 65536.0f)
// per-addend bias for packed u64 adds: guarantees positive 32-bit halves so
// low word never carries into high. |a| < 2^19, deg <= ~40 -> sum < 2^26.
#define FXBIAS (1 << 20)

// ---------------------------------------------------------------------------
// fp8 e4m3fn helpers (OCP).
#if __has_builtin(__builtin_amdgcn_cvt_f32_fp8) && __has_builtin(__builtin_amdgcn_cvt_pk_fp8_f32)
__device__ __forceinline__ float fp8_dec(unsigned char v) {
    return __builtin_amdgcn_cvt_f32_fp8((int)v, 0);
}
__device__ __forceinline__ unsigned fp8_pk4(float a, float b, float c, float d) {
    int w = __builtin_amdgcn_cvt_pk_fp8_f32(a, b, 0, false);
    w = __builtin_amdgcn_cvt_pk_fp8_f32(c, d, w, true);
    return (unsigned)w;
}
#else
__device__ __forceinline__ unsigned char fp8_enc1(float f) {
    unsigned u = __float_as_uint(f);
    unsigned s = (u >> 24) & 0x80u;
    u &= 0x7FFFFFFFu;
    if (u >= 0x43E00000u) return (unsigned char)(s | 0x7E);
    if (u < 0x3C800000u) {
        float a = __uint_as_float(u);
        int m = (int)rintf(a * 512.f);
        return (unsigned char)(s | (unsigned)m);
    }
    unsigned mant = u & 0x7FFFFFu;
    unsigned rest = mant & 0xFFFFFu;
    unsigned keep = u >> 20;
    keep += (rest > 0x80000u || (rest == 0x80000u && (keep & 1u))) ? 1u : 0u;
    int eb = (int)(keep >> 3) - 127 + 7;
    return (unsigned char)(s | (unsigned)((eb << 3) | (int)(keep & 7u)));
}
__device__ __forceinline__ float fp8_dec(unsigned char v) {
    unsigned s = ((unsigned)(v & 0x80u)) << 24;
    unsigned e = (v >> 3) & 0xFu;
    unsigned m = v & 7u;
    if (e == 0) {
        float r = (float)m * 0.001953125f;
        return (v & 0x80u) ? -r : r;
    }
    return __uint_as_float(s | ((e + 120u) << 23) | (m << 20));
}
__device__ __forceinline__ unsigned fp8_pk4(float a, float b, float c, float d) {
    return (unsigned)fp8_enc1(a) | ((unsigned)fp8_enc1(b) << 8) |
           ((unsigned)fp8_enc1(c) << 16) | ((unsigned)fp8_enc1(d) << 24);
}
#endif

#if __has_builtin(__builtin_amdgcn_cvt_pk_f32_fp8)
typedef float __attribute__((ext_vector_type(2))) f32x2;
__device__ __forceinline__ void fp8_dec4(unsigned w, float& a, float& b, float& c, float& d) {
    f32x2 lo = __builtin_amdgcn_cvt_pk_f32_fp8((int)w, false);
    f32x2 hi = __builtin_amdgcn_cvt_pk_f32_fp8((int)w, true);
    a = lo[0]; b = lo[1]; c = hi[0]; d = hi[1];
}
#else
__device__ __forceinline__ void fp8_dec4(unsigned w, float& a, float& b, float& c, float& d) {
    a = fp8_dec((unsigned char)(w & 0xFFu));
    b = fp8_dec((unsigned char)((w >> 8) & 0xFFu));
    c = fp8_dec((unsigned char)((w >> 16) & 0xFFu));
    d = fp8_dec((unsigned char)((w >> 24) & 0xFFu));
}
#endif

// pack two biased s16.16 addends into one u64 for ds_add_u64
__device__ __forceinline__ unsigned long long pack2(float f0, float f1) {
    unsigned lo = (unsigned)(FXBIAS + (int)(f0 * FXS));
    unsigned hi = (unsigned)(FXBIAS + (int)(f1 * FXS));
    return (unsigned long long)lo | ((unsigned long long)hi << 32);
}

// ---------------------------------------------------------------------------
// K_PART1: level-1 partition by super-bucket (dst >> 13, 64 bins).
// Record = (src << 13) | (dst & 8191) -- exactly 32 bits for src < 2^19.
__global__ __launch_bounds__(TPB_P) void k_part1(const int* __restrict__ src,
                                                 const int* __restrict__ dst,
                                                 int* __restrict__ bcur1,   // [64*16] zeroed
                                                 int* __restrict__ grec1,   // [NS1*CAP1]
                                                 int E) {
    __shared__ int hist[NS1], lstart[NS1], lcur[NS1], gbase[NS1];
    __shared__ int lbuf[CHUNK];
    __shared__ unsigned char bbuf[CHUNK];
    int t = threadIdx.x;
    int chunkBase = blockIdx.x * CHUNK;
    if (t < NS1) hist[t] = 0;
    __syncthreads();

    int myb[CPT], myrec[CPT];
#pragma unroll
    for (int k = 0; k < CPT; k++) {
        int e = chunkBase + k * TPB_P + t;
        if (e < E) {
            int d = dst[e];
            int s = src[e];
            myb[k] = d >> LOG_SUP;
            myrec[k] = (s << LOG_SUP) | (d & ((1 << LOG_SUP) - 1));
            atomicAdd(&hist[myb[k]], 1);
        } else myb[k] = -1;
    }
    __syncthreads();
    if (t == 0) {
        int run = 0;
        for (int k2 = 0; k2 < NS1; k2++) {
            int c = hist[k2]; lstart[k2] = run; lcur[k2] = run; run += c;
        }
    }
    __syncthreads();
    if (t < NS1 && hist[t] > 0) gbase[t] = atomicAdd(&bcur1[t * 16], hist[t]);
    __syncthreads();
#pragma unroll
    for (int k = 0; k < CPT; k++) {
        if (myb[k] >= 0) {
            int p = atomicAdd(&lcur[myb[k]], 1);
            lbuf[p] = myrec[k];
            bbuf[p] = (unsigned char)myb[k];
        }
    }
    __syncthreads();
    int total = E - chunkBase; if (total > CHUNK) total = CHUNK;
    for (int p = t; p < total; p += TPB_P) {
        int b = (int)bbuf[p];
        int pos = gbase[b] + (p - lstart[b]);
        if (pos < CAP1) grec1[(size_t)b * CAP1 + pos] = lbuf[p];
    }
}

// K_PART2: level-2 partition of each super-bucket into its 8 final buckets.
// Record transform (src<<13)|(dst&8191) -> (src<<10)|(dst&1023).
__global__ __launch_bounds__(TPB_P) void k_part2(const int* __restrict__ bcur1,
                                                 const int* __restrict__ grec1,
                                                 int* __restrict__ bcur,
                                                 int* __restrict__ grec) {
    __shared__ int hist[NS2], lstart[NS2], lcur[NS2], gbase[NS2];
    __shared__ int lbuf[CHUNK];
    __shared__ unsigned char bbuf[CHUNK];
    int t = threadIdx.x;
    int s = blockIdx.x;
    int cnt1 = bcur1[s * 16]; if (cnt1 > CAP1) cnt1 = CAP1;
    int chunkBase = blockIdx.y * CHUNK;
    if (chunkBase >= cnt1) return;             // uniform per block
    int total = cnt1 - chunkBase; if (total > CHUNK) total = CHUNK;
    if (t < NS2) hist[t] = 0;
    __syncthreads();

    int myb[CPT], myrec[CPT];
#pragma unroll
    for (int k = 0; k < CPT; k++) {
        int i = chunkBase + k * TPB_P + t;
        if (i < cnt1) {
            int r = grec1[(size_t)s * CAP1 + i];
            int sub = (r >> LOG_NPB) & (NS2 - 1);
            myb[k] = sub;
            myrec[k] = (int)((((unsigned)r) >> LOG_SUP) << LOG_NPB) | (r & (NPB - 1));
            atomicAdd(&hist[sub], 1);
        } else myb[k] = -1;
    }
    __syncthreads();
    if (t == 0) {
        int run = 0;
        for (int k2 = 0; k2 < NS2; k2++) {
            int c = hist[k2]; lstart[k2] = run; lcur[k2] = run; run += c;
        }
    }
    __syncthreads();
    if (t < NS2 && hist[t] > 0) gbase[t] = atomicAdd(&bcur[(s * NS2 + t) * 16], hist[t]);
    __syncthreads();
#pragma unroll
    for (int k = 0; k < CPT; k++) {
        if (myb[k] >= 0) {
            int p = atomicAdd(&lcur[myb[k]], 1);
            lbuf[p] = myrec[k];
            bbuf[p] = (unsigned char)myb[k];
        }
    }
    __syncthreads();
    for (int p = t; p < total; p += TPB_P) {
        int b = (int)bbuf[p];
        int pos = gbase[b] + (p - lstart[b]);
        if (pos < CAP) grec[(size_t)(s * NS2 + b) * CAP + pos] = lbuf[p];
    }
}

// K_SORT: per-bucket counting sort by src-tile (rec >> 23 == src >> 13).
// Also computes deg/dinv. 512 threads, ~119KB LDS.
__global__ __launch_bounds__(TPB_P) void k_sort(int* __restrict__ bcur,
                                                int* __restrict__ grec,
                                                float* __restrict__ dinv, int N) {
    __shared__ int lbuf[CAP];     // 57344 B
    __shared__ int obuf[CAP];     // 57344 B
    __shared__ int deg[NPB];      // 4096 B
    __shared__ int hist[NTILE];
    __shared__ int curp[NTILE];
    int t = threadIdx.x;
    int b = blockIdx.x;
    int cnt = bcur[b * 16]; if (cnt > CAP) cnt = CAP;
    const size_t base = (size_t)b * CAP;

    for (int i = t; i < NTILE; i += TPB_P) hist[i] = 0;
    for (int i = t; i < NPB; i += TPB_P) deg[i] = 0;
    __syncthreads();
    for (int i = t; i < cnt; i += TPB_P) {
        int r = grec[base + i];
        lbuf[i] = r;
        atomicAdd(&deg[r & (NPB - 1)], 1);
        atomicAdd(&hist[((unsigned)r) >> 23], 1);   // int LDS atomic: native
    }
    __syncthreads();
    if (t == 0) {
        int run = 0;
#pragma unroll
        for (int k = 0; k < NTILE; k++) { int c = hist[k]; curp[k] = run; run += c; }
    }
    __syncthreads();
    for (int i = t; i < cnt; i += TPB_P) {
        int r = lbuf[i];
        int p = atomicAdd(&curp[((unsigned)r) >> 23], 1);
        obuf[p] = r;
    }
    __syncthreads();
    for (int i = t; i < cnt; i += TPB_P) grec[base + i] = obuf[i];
    int nodeBase = b << LOG_NPB;
    for (int i = t; i < NPB; i += TPB_P) {
        int node = nodeBase + i;
        if (node < N) dinv[node] = rsqrtf((float)(deg[i] + 1));
    }
}

// ---------------------------------------------------------------------------
// K3: hp = fp8_e4m3( dinv * (x @ W.T) )
__global__ __launch_bounds__(TPB) void k_h(const float* __restrict__ xc,
                                           const float* __restrict__ W,
                                           const float* __restrict__ dinv,
                                           unsigned* __restrict__ hp, int n) {
    __shared__ float sW[256];
    if (threadIdx.x < 256) sW[threadIdx.x] = W[threadIdx.x];
    __syncthreads();
    int i = blockIdx.x * blockDim.x + threadIdx.x;
    int stride = gridDim.x * blockDim.x;
    for (; i < n; i += stride) {
        float x[16];
        const float4* xr = (const float4*)(xc + (size_t)i * 16);
#pragma unroll
        for (int q = 0; q < 4; q++) {
            float4 v = xr[q];
            x[4*q+0] = v.x; x[4*q+1] = v.y; x[4*q+2] = v.z; x[4*q+3] = v.w;
        }
        float di = dinv[i];
        float hv[16];
#pragma unroll
        for (int j = 0; j < 16; j++) {
            float s = 0.f;
#pragma unroll
            for (int k = 0; k < 16; k++) s = fmaf(x[k], sW[j*16 + k], s);
            hv[j] = di * s;
        }
        uint4 w;
        w.x = fp8_pk4(hv[0],  hv[1],  hv[2],  hv[3]);
        w.y = fp8_pk4(hv[4],  hv[5],  hv[6],  hv[7]);
        w.z = fp8_pk4(hv[8],  hv[9],  hv[10], hv[11]);
        w.w = fp8_pk4(hv[12], hv[13], hv[14], hv[15]);
        ((uint4*)hp)[i] = w;
    }
}

// ---------------------------------------------------------------------------
// K_AGG: edge-parallel aggregation + finalize, ONE block per 1024-node
// bucket (r4 config: 2 blocks/CU, 16 waves/CU, 512-edge chunks, FETCH 61.5MB).
// Phase 1: 4 lanes/edge; each lane decodes 4 fp8 features and issues TWO
// ds_add_u64 (feature pairs, biased positive halves) instead of 4 ds_add_u32
// -- halves LDS-pipe instructions.
// Phase 2: finalize removes bias using in-bucket degree recovered from dinv;
// z = relu(dinv*(acc+self)+b); dW/db reduced via red[512][17] overlay.
__global__ __launch_bounds__(TPB_A, 4) void k_agg(const int* __restrict__ bcur,
                                                  const int* __restrict__ grec,
                                                  const float* __restrict__ dinv,
                                                  const unsigned* __restrict__ hp32,
                                                  const float* __restrict__ b,
                                                  const float* __restrict__ xc,
                                                  float* __restrict__ z,
                                                  float* __restrict__ partial,
                                                  int nb, int N) {
    __shared__ unsigned long long accP[8 * NPB];   // 64 KB; red overlay later
    int t = threadIdx.x;
    int bkt = blockIdx.x;
    int cnt = bcur[bkt * 16]; if (cnt > CAP) cnt = CAP;
    const int nodeBase = bkt << LOG_NPB;
    const size_t recBase = (size_t)bkt * CAP;

    for (int i = t; i < 8 * NPB; i += TPB_A) accP[i] = 0ull;
    __syncthreads();

    // ---- Phase 1: edge-parallel scatter (packed biased u64 atomics) ----
    int q = t & 3;          // hp dword q -> features 4q..4q+3 -> pairs 2q, 2q+1
    int gi = t >> 2;        // edge slot 0..127
    int p0 = q * 2;
    int p1 = q * 2 + 1;
    int base = 0;
    for (; base + 512 <= cnt; base += 512) {
        int rec[4];
#pragma unroll
        for (int u = 0; u < 4; u++) rec[u] = grec[recBase + base + u * 128 + gi];
        unsigned w[4];
#pragma unroll
        for (int u = 0; u < 4; u++)
            w[u] = hp32[(size_t)(((unsigned)rec[u]) >> LOG_NPB) * 4 + q];
#pragma unroll
        for (int u = 0; u < 4; u++) {
            int dl = rec[u] & (NPB - 1);
            float f0, f1, f2, f3;
            fp8_dec4(w[u], f0, f1, f2, f3);
            atomicAdd(&accP[p0 * NPB + (dl ^ p0)], pack2(f0, f1));
            atomicAdd(&accP[p1 * NPB + (dl ^ p1)], pack2(f2, f3));
        }
    }
    for (int e = base + gi; e < cnt; e += 128) {
        int rec = grec[recBase + e];
        unsigned w = hp32[(size_t)(((unsigned)rec) >> LOG_NPB) * 4 + q];
        int dl = rec & (NPB - 1);
        float f0, f1, f2, f3;
        fp8_dec4(w, f0, f1, f2, f3);
        atomicAdd(&accP[p0 * NPB + (dl ^ p0)], pack2(f0, f1));
        atomicAdd(&accP[p1 * NPB + (dl ^ p1)], pack2(f2, f3));
    }
    __syncthreads();

    // ---- Phase 2: finalize rows (16 lanes per row, 32 row-groups) ----
    const unsigned char* hpB = (const unsigned char*)hp32;
    const int* accI32 = (const int*)accP;
    int j = t & 15;
    int g0 = t >> 4;        // 0..31 row groups
    int pj = j >> 1;        // pair plane
    int hj = j & 1;         // half within pair
    float bj = b[j];
    float accW[16];
#pragma unroll
    for (int k = 0; k < 16; k++) accW[k] = 0.f;
    float accB = 0.f;

    for (int i = g0; i < NPB; i += 32) {
        int node = nodeBase + i;
        if (node >= N) break;
        float di = dinv[node];
        // in-bucket degree (atomic-add count) recovered from dinv = rsqrt(deg+1)
        int cdeg = (int)rintf(1.0f / (di * di)) - 1;
        int raw = accI32[(pj * NPB + (i ^ pj)) * 2 + hj];
        int ai = raw - cdeg * FXBIAS;                        // remove per-add bias
        float sv = fp8_dec(hpB[(size_t)node * 16 + j]);      // self-loop
        float aj = fmaf((float)ai, FXSI, sv);
        float zj = fmaxf(fmaf(di, aj, bj), 0.f);
        z[(size_t)node * 16 + j] = zj;
        float wdj = 4.f * zj * zj;
        accB += wdj;
        const float4* xrow = (const float4*)(xc + (size_t)node * 16);
        float4 x0 = xrow[0], x1 = xrow[1], x2 = xrow[2], x3 = xrow[3];
        accW[0]  = fmaf(x0.x, wdj, accW[0]);  accW[1]  = fmaf(x0.y, wdj, accW[1]);
        accW[2]  = fmaf(x0.z, wdj, accW[2]);  accW[3]  = fmaf(x0.w, wdj, accW[3]);
        accW[4]  = fmaf(x1.x, wdj, accW[4]);  accW[5]  = fmaf(x1.y, wdj, accW[5]);
        accW[6]  = fmaf(x1.z, wdj, accW[6]);  accW[7]  = fmaf(x1.w, wdj, accW[7]);
        accW[8]  = fmaf(x2.x, wdj, accW[8]);  accW[9]  = fmaf(x2.y, wdj, accW[9]);
        accW[10] = fmaf(x2.z, wdj, accW[10]); accW[11] = fmaf(x2.w, wdj, accW[11]);
        accW[12] = fmaf(x3.x, wdj, accW[12]); accW[13] = fmaf(x3.y, wdj, accW[13]);
        accW[14] = fmaf(x3.z, wdj, accW[14]); accW[15] = fmaf(x3.w, wdj, accW[15]);
    }
    __syncthreads();   // all accP reads done -> safe to alias red onto accP

    float (*red)[17] = (float (*)[17])accP;   // 512*17*4 = 34816B <= 64KB
#pragma unroll
    for (int k = 0; k < 16; k++) red[t][k] = accW[k];
    red[t][16] = accB;
    __syncthreads();
    if (t < 256) {
        int kk = t >> 4;
        int jj = t & 15;
        float s = 0.f;
#pragma unroll
        for (int g = 0; g < 32; g++) s += red[g * 16 + jj][kk];
        partial[(size_t)(kk * 16 + jj) * nb + bkt] = s;
    }
    if (t < 16) {
        float sb = 0.f;
#pragma unroll
        for (int g = 0; g < 32; g++) sb += red[g * 16 + t][16];
        partial[(size_t)(256 + t) * nb + bkt] = sb;
    }
}

// K5b: one 64-lane wave per (layer,elem), 52 blocks: coalesced memory-parallel
// sum over nb partials. (Round-7 lesson: a single-block merged reduce is
// latency-bound at 163us -- one CU can't generate enough MLP.)
__global__ __launch_bounds__(TPB) void k_reduce(const float* __restrict__ partial,
                                                float* __restrict__ acc,
                                                int nb, int total) {
    int wid = (blockIdx.x * blockDim.x + threadIdx.x) >> 6;
    int lane = threadIdx.x & 63;
    if (wid >= total) return;
    const float* p = partial + (size_t)wid * nb;
    float s = 0.f;
    for (int b = lane; b < nb; b += 64) s += p[b];
#pragma unroll
    for (int off = 32; off > 0; off >>= 1) s += __shfl_down(s, off, 64);
    if (lane == 0) acc[wid] = s;
}

// ---------------------------------------------------------------------------
__device__ __forceinline__ float local_loss_f(float g, int positive) {
    const float t = 0.0f;
    if (positive) {
        if (g > t + 10.f) return 0.f;
        if (g < t - 10.f) return t - g;
        return log1pf(expf(t - g));
    } else {
        if (g > t + 10.f) return t + g;
        if (g < t - 10.f) return 0.f;
        return log1pf(expf(g + t));
    }
}

__global__ void k_final(const float* __restrict__ W1, const float* __restrict__ b1,
                        const float* __restrict__ acc, const int* __restrict__ positive,
                        float* __restrict__ outv) {
    int t = threadIdx.x;
    if (t < 256) {
        int jj = t >> 4, kk = t & 15;   // Wc[jj][kk] -= LR * dW[kk][jj]
        float s = 0.f;
#pragma unroll
        for (int l = 0; l < 3; l++) s += acc[l * 272 + kk * 16 + jj];
        outv[1 + t] = W1[t] - LRATE * s;
    }
    if (t < 16) {
        float s = 0.f;
#pragma unroll
        for (int l = 0; l < 3; l++) s += acc[l * 272 + 256 + t];
        outv[257 + t] = b1[t] - LRATE * s;
    }
    if (t == 0) {
        int pos = positive[0];
        float agg = 0.f;
#pragma unroll
        for (int l = 0; l < 3; l++) {
            float g = 0.f;
#pragma unroll
            for (int jj = 0; jj < 16; jj++) g += acc[l * 272 + 256 + jj];
            g *= (1.0f / 64.0f);
            agg += local_loss_f(g, pos);
        }
        outv[0] = agg;
    }
}

extern "C" void kernel_launch(void* const* d_in, const int* in_sizes, int n_in,
                              void* d_out, int out_size, void* d_ws, size_t ws_size,
                              hipStream_t stream) {
    const float* x  = (const float*)d_in[0];
    const int*   ei = (const int*)d_in[1];
    const float* W1 = (const float*)d_in[2];
    const float* b1 = (const float*)d_in[3];
    const float* W2 = (const float*)d_in[4];
    const float* b2 = (const float*)d_in[5];
    const float* W3 = (const float*)d_in[6];
    const float* b3 = (const float*)d_in[7];
    const int* positive = (const int*)d_in[8];
    float* outv = (float*)d_out;

    const int N = in_sizes[0] / 16;
    const int E = in_sizes[1] / 2;
    const int nbuck = (N + NPB - 1) >> LOG_NPB;         // 489 for N=500k
    const int nsuper = (N + (1 << LOG_SUP) - 1) >> LOG_SUP;   // 62
    const int nbpad = nsuper * NS2;                     // 496 (grec/bcur sizing)

    // Workspace carve-out (256B aligned).
    char* ws = (char*)d_ws;
    size_t off = 0;
    auto carve = [&](size_t bytes) -> void* {
        void* p = ws + off;
        off = (off + bytes + 255) & ~(size_t)255;
        return p;
    };
    int*   bcur   = (int*)  carve((size_t)(nbpad + NS1) * 16 * 4);  // bucket + super cursors
    int*   bcur1  = bcur + (size_t)nbpad * 16;
    int*   grec   = (int*)  carve((size_t)nbpad * CAP * 4);   // 28.4 MB, lives all layers
    float* dinv   = (float*)carve((size_t)N * 4);
    float* acc    = (float*)carve(3 * 272 * 4);
    float* part   = (float*)carve((size_t)3 * 272 * nbuck * 4);
    unsigned* hp  = (unsigned*)carve((size_t)N * 16);         // fp8 rows, 8 MB
    float* P1     = (float*)carve((size_t)N * 64);
    // grec1 (22.3 MB, dead after k_part2) aliases P2 (32 MB, first written
    // by k_agg in layer 2 -- strictly after k_part2).
    float* P2     = (float*)carve((size_t)N * 64);
    int*   grec1  = (int*)P2;

    hipMemsetAsync(bcur, 0, (size_t)(nbpad + NS1) * 16 * 4, stream);

    const int* src = ei;
    const int* dst = ei + E;

    // --- Two-level partition + src-tile sort (once, reused 3x) ---
    int p1Blocks = (E + CHUNK - 1) / CHUNK;
    k_part1<<<p1Blocks, TPB_P, 0, stream>>>(src, dst, bcur1, grec1, E);
    dim3 g2(nsuper, CAP1 / CHUNK);     // (62, 22)
    k_part2<<<g2, TPB_P, 0, stream>>>(bcur1, grec1, bcur, grec);
    k_sort<<<nbuck, TPB_P, 0, stream>>>(bcur, grec, dinv, N);

    // --- 3 layers ---
    const float* Ws[3] = {W1, W2, W3};
    const float* bss[3] = {b1, b2, b3};
    float* outs[3] = {P1, P2, P1};   // L1: x->P1; L2: P1->P2; L3: P2->P1

    int nodeBlocks = (N + TPB - 1) / TPB;

    const float* xc = x;
    for (int l = 0; l < 3; l++) {
        k_h<<<nodeBlocks, TPB, 0, stream>>>(xc, Ws[l], dinv, hp, N);
        k_agg<<<nbuck, TPB_A, 0, stream>>>(bcur, grec, dinv, hp, bss[l],
                                           xc, outs[l],
                                           part + (size_t)l * 272 * nbuck, nbuck, N);
        xc = outs[l];
    }
    int totalElems = 3 * 272;
    k_reduce<<<(totalElems * 64 + TPB - 1) / TPB, TPB, 0, stream>>>(part, acc, nbuck, totalElems);
    k_final<<<1, 256, 0, stream>>>(W1, b1, acc, positive, outv);
}